// Round 8
// baseline (89.418 us; speedup 1.0000x reference)
//
#include <hip/hip_runtime.h>
#include <math.h>

#define IMG 256
#define NPIX (IMG*IMG)
#define SIGMA_INV 100.0f
#define EPSF 1e-6f
#define LOG2E 1.4426950408889634f
#define TANV 0.5773502691896258f   // tan(30 deg)
#define TSKIP 24.0f
#define NGROUP 4                   // part layers; 4 waves (chunks) per block
#define NSBLK (1024*NGROUP)        // 4096 sil blocks
#define NLBLK 128                  // loss blocks (128*512 = NPIX)

__device__ __forceinline__ float fexp2(float x) {
#if __has_builtin(__builtin_amdgcn_exp2f)
  return __builtin_amdgcn_exp2f(x);
#else
  return exp2f(x);
#endif
}
__device__ __forceinline__ float frcp(float x) {
#if __has_builtin(__builtin_amdgcn_rcpf)
  return __builtin_amdgcn_rcpf(x);
#else
  return 1.0f / x;
#endif
}
__device__ __forceinline__ float rlane(float x, int j) {
#if __has_builtin(__builtin_amdgcn_readlane)
  return __int_as_float(__builtin_amdgcn_readlane(__float_as_int(x), j));
#else
  return __shfl(x, j);
#endif
}

// Contraction-off cross product (sign(area) of non-degenerate faces).
__device__ __forceinline__ float cross2(float ax, float ay, float bx, float by) {
#pragma clang fp contract(off)
  return ax * by - ay * bx;
}

// Fused silhouette kernel. Block = (tile, group) from swizzled blockIdx;
// 4 waves/block, wave w owns the 64-face chunk (4*group+w). Each lane
// computes ITS face's edge constants inline from verts/faces/cam (no prep
// kernel, no fd workspace, no dependency). Phase 1: lane-parallel relevance
// (conservative tile bound). Phase 2: uniform ctz bit-loop; constants
// broadcast from the owning lane's registers via v_readlane (no memory).
// Faces with a repeated vertex INDEX get s=0 exactly (matches numpy's
// exact-zero area -> sign=0 -> frag=1/8 everywhere; dominates the loss).
__global__ __launch_bounds__(256) void sil_kernel(
    const float* __restrict__ verts, const int* __restrict__ faces,
    const float* __restrict__ cam, float* __restrict__ part, int F) {
  __shared__ float s_part[NGROUP * 64];

  int q = (blockIdx.x * 1637) & (NSBLK - 1);   // odd mult: bijection mod 4096
  int tile = q >> 2, group = q & 3;
  int tid = threadIdx.x;
  int lane = tid & 63, w = tid >> 6;
  int bx = tile & 31, by = tile >> 5;
  int ix = (bx << 3) + (lane & 7);
  int iy = (by << 3) + (lane >> 3);
  float px = (2.0f * (float)ix + 1.0f) * (1.0f / IMG) - 1.0f;
  float py = 1.0f - (2.0f * (float)iy + 1.0f) * (1.0f / IMG);
  float cx = ((float)(16 * bx + 8)) * (1.0f / IMG) - 1.0f;
  float cy = 1.0f - ((float)(16 * by + 8)) * (1.0f / IMG);
  const float h = 7.0f / IMG;                  // tile half-extent (centers)

  // ---- inline prep: this lane's face = chunk base + lane ----
  int f = (group * 4 + w) * 64 + lane;
  int fc = (f < F) ? f : F - 1;                // clamped for safe loads

  float ex = cam[0], ey = cam[1], ez = cam[2];
  float zn = sqrtf(ex * ex + ey * ey + ez * ez) + EPSF;
  float izn = frcp(zn);
  float zx = -ex * izn, zy = -ey * izn, zz = -ez * izn;
  float xn = sqrtf(zz * zz + zx * zx) + EPSF;
  float ixn = frcp(xn);
  float xx = zz * ixn, xz = -zx * ixn;         // xy = 0
  float yx = zy * xz;                          // cross(z,x) with xy=0
  float yy = zz * xx - zx * xz;
  float yz = -zy * xx;

  int i0 = faces[3 * fc + 0], i1 = faces[3 * fc + 1], i2 = faces[3 * fc + 2];
  bool deg = (i0 == i1) | (i1 == i2) | (i0 == i2);
  int vi_[3] = {i0, i1, i2};
  float pxs[3], pys[3];
#pragma unroll
  for (int k = 0; k < 3; ++k) {
    int vi = vi_[k];
    float ax = verts[3 * vi + 0] - ex;
    float ay = verts[3 * vi + 1] - ey;
    float az = verts[3 * vi + 2] - ez;
    float vx = ax * xx + az * xz;
    float vy = ax * yx + ay * yy + az * yz;
    float vz = ax * zx + ay * zy + az * zz;
    float izw = frcp(vz * TANV);
    pxs[k] = vx * izw;
    pys[k] = vy * izw;
  }
  float e01x = pxs[1] - pxs[0], e01y = pys[1] - pys[0];
  float e02x = pxs[2] - pxs[0], e02y = pys[2] - pys[0];
  float area = cross2(e01x, e01y, e02x, e02y);
  float s = deg ? 0.0f
                : ((area > 0.0f) ? 1.0f : ((area < 0.0f) ? -1.0f : 0.0f));
  float K = -s * SIGMA_INV * LOG2E;
  float c0x, c0y, c0z, c1x, c1y, c1z, c2x, c2y, c2z;
#pragma unroll
  for (int k = 0; k < 3; ++k) {
    int kn = (k == 2) ? 0 : k + 1;
    float dx = pxs[kn] - pxs[k], dy = pys[kn] - pys[k];
    float il = frcp(sqrtf(dx * dx + dy * dy) + EPSF);
    float nx = -dy * il, ny = dx * il;
    float c = pxs[k] * nx + pys[k] * ny;
    float ox = nx * K, oy = ny * K, oz = -c * K;
    if (k == 0) { c0x = ox; c0y = oy; c0z = oz; }
    else if (k == 1) { c1x = ox; c1y = oy; c1z = oz; }
    else { c2x = ox; c2y = oy; c2z = oz; }
  }

  // ---- phase 1: relevance of this lane's face for the whole tile ----
  float m0 = fmaf(cx, c0x, fmaf(cy, c0y, c0z)) - (fabsf(c0x) + fabsf(c0y)) * h;
  float m1 = fmaf(cx, c1x, fmaf(cy, c1y, c1z)) - (fabsf(c1x) + fabsf(c1y)) * h;
  float m2 = fmaf(cx, c2x, fmaf(cy, c2y, c2z)) - (fabsf(c2x) + fabsf(c2y)) * h;
  bool rel = (f < F) && (fmaxf(m0, fmaxf(m1, m2)) < TSKIP);
  unsigned long long mask = __ballot(rel ? 1 : 0);

  // ---- phase 2: uniform bit-loop over relevant faces ----
  float acc = 1.0f;
  while (mask) {
    int j = __builtin_ctzll(mask);
    mask &= mask - 1;
    float b0x = rlane(c0x, j), b0y = rlane(c0y, j), b0z = rlane(c0z, j);
    float b1x = rlane(c1x, j), b1y = rlane(c1y, j), b1z = rlane(c1z, j);
    float b2x = rlane(c2x, j), b2y = rlane(c2y, j), b2z = rlane(c2z, j);
    float t0 = fmaf(px, b0x, fmaf(py, b0y, b0z));
    float t1 = fmaf(px, b1x, fmaf(py, b1y, b1z));
    float t2 = fmaf(px, b2x, fmaf(py, b2y, b2z));
    float D = (1.0f + fexp2(t0)) * (1.0f + fexp2(t1)) * (1.0f + fexp2(t2));
    acc = fmaf(-frcp(D), acc, acc);            // acc *= 1 - 1/D
  }

  s_part[w * 64 + lane] = acc;
  __syncthreads();

  if (w == 0) {
    float p = s_part[lane] * s_part[64 + lane] *
              s_part[128 + lane] * s_part[192 + lane];
    part[group * NPIX + iy * IMG + ix] = p;
  }
}

// Combine the 4 group layers, squared error vs ref, block-reduce,
// one atomicAdd per block into out[0] (zeroed by the memset node).
__global__ __launch_bounds__(512) void loss_kernel(const float* __restrict__ part,
                                                   const float* __restrict__ ref,
                                                   float* __restrict__ out) {
  int p = blockIdx.x * 512 + threadIdx.x;
  float a = part[p] * part[p + NPIX] * part[p + 2 * NPIX] * part[p + 3 * NPIX];
  float d = (1.0f - a) - ref[p];
  float v = d * d;
#pragma unroll
  for (int off = 32; off > 0; off >>= 1) v += __shfl_down(v, off);
  __shared__ float red[8];
  if ((threadIdx.x & 63) == 0) red[threadIdx.x >> 6] = v;
  __syncthreads();
  if (threadIdx.x == 0) {
    float t = 0.0f;
#pragma unroll
    for (int c = 0; c < 8; ++c) t += red[c];
    atomicAdd(out, t);
  }
}

extern "C" void kernel_launch(void* const* d_in, const int* in_sizes, int n_in,
                              void* d_out, int out_size, void* d_ws, size_t ws_size,
                              hipStream_t stream) {
  const float* verts = (const float*)d_in[0];
  const int* faces = (const int*)d_in[1];
  const float* cam = (const float*)d_in[2];
  const float* imref = (const float*)d_in[3];
  int V = in_sizes[0] / 3;  (void)V;
  int F = in_sizes[1] / 3;  // 1000
  float* out = (float*)d_out;
  float* part = (float*)d_ws;   // NGROUP * NPIX floats (1 MB)

  hipMemsetAsync(out, 0, sizeof(float), stream);
  sil_kernel<<<NSBLK, 256, 0, stream>>>(verts, faces, cam, part, F);
  loss_kernel<<<NLBLK, 512, 0, stream>>>(part, imref, out);
}